// Round 8
// baseline (843.301 us; speedup 1.0000x reference)
//
#include <hip/hip_runtime.h>
#include <hip/hip_bf16.h>

#define NN 4096
#define EE 2048
#define RR 4
#define FF 128
#define HDD 256

typedef __attribute__((ext_vector_type(4))) float floatx4;
typedef __attribute__((ext_vector_type(8))) __bf16 bf16x8;

#define AS1 __attribute__((address_space(1)))
#define AS3 __attribute__((address_space(3)))

__device__ __forceinline__ void async16(const void* g, void* l) {
  __builtin_amdgcn_global_load_lds((const AS1 void*)(unsigned long long)(g),
                                   (AS3 void*)(unsigned int)(unsigned long long)(l),
                                   16, 0, 0);
}

__device__ inline unsigned short f2b(float x) {
  unsigned int u = __float_as_uint(x);
  unsigned int r = u + 0x7fffu + ((u >> 16) & 1u);
  return (unsigned short)(r >> 16);
}
__device__ inline float b2f(unsigned short u) { return __uint_as_float((unsigned int)u << 16); }

__device__ inline float rel_w(const float* rel, int r) {
  float m = fmaxf(fmaxf(rel[0], rel[1]), fmaxf(rel[2], rel[3]));
  float s = 0.f;
#pragma unroll
  for (int i = 0; i < RR; i++) s += expf(rel[i] - m);
  return expf(rel[r] - m) / s;
}

// ---- pass over H: row sums -> dvs[r][n] = rw*rsqrt(rw*sum+eps), plus 0/1 bitmask ----
__global__ void k_dvmask(const float* __restrict__ H, const float* __restrict__ rel,
                         float* __restrict__ dvs, unsigned long long* __restrict__ mask) {
  int wave = (blockIdx.x << 2) | (threadIdx.x >> 6);  // = r*NN + n
  int lane = threadIdx.x & 63;
  int r = wave >> 12;
  const float* row = H + (size_t)wave * EE;
  unsigned long long* mrow = mask + (size_t)wave * (EE / 64);
  float s = 0.f;
  for (int j = 0; j < EE / 64; j++) {
    float h = row[j * 64 + lane];
    s += h;
    unsigned long long m = __ballot(h != 0.0f);
    if (lane == 0) mrow[j] = m;
  }
  for (int off = 32; off; off >>= 1) s += __shfl_down(s, off);
  if (lane == 0) {
    float rwr = rel_w(rel, r);
    dvs[wave] = rwr * rsqrtf(rwr * s + 1e-8f);
  }
}

// ---- column counts + TRANSPOSED bitmask via ballot bit-transpose ----
// maskT[r][e][NN/64 words]: bit j of word w_n = H[r][n0+j][e] != 0
__global__ void k_de_pop(const unsigned long long* __restrict__ mask, float* __restrict__ de_acc,
                         unsigned long long* __restrict__ maskT) {
  int wid = threadIdx.x >> 6, lane = threadIdx.x & 63;
  int wcol = blockIdx.x, r = blockIdx.z;
  int n0 = (blockIdx.y << 8) + (wid << 6);
  unsigned long long w = mask[(size_t)(r * NN + n0 + lane) * (EE / 64) + wcol];
  float cnt = 0.f;
  unsigned long long mym = 0;
#pragma unroll
  for (int b = 0; b < 64; b++) {
    unsigned long long m = __ballot(((w >> b) & 1ULL) != 0);
    if (lane == b) { cnt = (float)__popcll(m); mym = m; }
  }
  atomicAdd(&de_acc[r * EE + (wcol << 6) + lane], cnt);
  maskT[((size_t)r * EE + (wcol << 6) + lane) * (NN / 64) + (n0 >> 6)] = mym;
}

// ---- flat f32 -> bf16 ----
__global__ void k_cvt(const float* __restrict__ src, unsigned short* __restrict__ dst) {
  int i = (blockIdx.x * 256 + threadIdx.x) * 4;
  float4 v = *(const float4*)(src + i);
  ushort4 o; o.x = f2b(v.x); o.y = f2b(v.y); o.z = f2b(v.z); o.w = f2b(v.w);
  *(ushort4*)(dst + i) = o;
}

// ---- all three weight transforms in ONE launch ----
__global__ void k_wprep(const float* __restrict__ W1, const float* __restrict__ W2,
                        const float* __restrict__ W3, const float* __restrict__ imp,
                        unsigned short* __restrict__ W1catT, unsigned short* __restrict__ W2T,
                        unsigned short* __restrict__ W3T) {
  int idx = blockIdx.x * 256 + threadIdx.x;
  if (idx < RR * FF * HDD) {
    int o = idx % HDD, f = (idx / HDD) % FF, r = idx / (HDD * FF);
    float sg = 1.0f / (1.0f + expf(-imp[r]));
    W1catT[(size_t)o * (RR * FF) + r * FF + f] = f2b(sg * W1[((size_t)r * FF + f) * HDD + o]);
  } else if (idx < RR * FF * HDD + RR * HDD * HDD) {
    int j = idx - RR * FF * HDD;
    int c = j % HDD, o = (j / HDD) % HDD, r = j / (HDD * HDD);
    float sg = 1.0f / (1.0f + expf(-imp[RR + r]));
    W2T[j] = f2b(sg * W2[((size_t)r * HDD + c) * HDD + o]);
  } else {
    int j = idx - RR * FF * HDD - RR * HDD * HDD;
    int c = j % HDD, o = (j / HDD) % FF, r = j / (HDD * FF);
    float sg = 1.0f / (1.0f + expf(-imp[2 * RR + r]));
    W3T[j] = f2b(sg * W3[((size_t)r * HDD + c) * FF + o]);
  }
}

// ---------------- SpMM-T: t[r][e][f] = de2[r][e] * sum_{n:bit} dvs[r][n] * Xin[(r)][n][f] ----------------
// one wave per (e, r); maskT words are wave-uniform; 4-wide unrolled bit scan.
template <int CPL>
__global__ void k_spmm_t(const unsigned short* __restrict__ Xin, long xin_rs,
                         const unsigned long long* __restrict__ maskT,
                         const float* __restrict__ dvs, const float* __restrict__ decnt,
                         const float* __restrict__ rel,
                         unsigned short* __restrict__ out) {
  const int F = CPL * 64;
  int wid = threadIdx.x >> 6, lane = threadIdx.x & 63;
  int e = (blockIdx.x << 2) | wid;
  int r = blockIdx.y;
  const unsigned long long* wrow = maskT + ((size_t)r * EE + e) * (NN / 64);
  const float* dv = dvs + r * NN;
  const unsigned short* Xc = Xin + (size_t)r * xin_rs + lane * CPL;
  float acc[CPL];
#pragma unroll
  for (int i = 0; i < CPL; i++) acc[i] = 0.f;
  for (int c = 0; c < NN / 64; c++) {
    unsigned long long m = wrow[c];
    int n0 = c << 6;
    while (m) {
      int j0 = __ffsll((long long)m) - 1; m &= m - 1;
      int j1 = j0, j2 = j0, j3 = j0;
      float w1 = 0.f, w2 = 0.f, w3 = 0.f;
      if (m) { j1 = __ffsll((long long)m) - 1; m &= m - 1; w1 = 1.f; }
      if (m) { j2 = __ffsll((long long)m) - 1; m &= m - 1; w2 = 1.f; }
      if (m) { j3 = __ffsll((long long)m) - 1; m &= m - 1; w3 = 1.f; }
      int n_0 = n0 + j0, n_1 = n0 + j1, n_2 = n0 + j2, n_3 = n0 + j3;
      float d0 = dv[n_0], d1 = w1 * dv[n_1], d2 = w2 * dv[n_2], d3 = w3 * dv[n_3];
      if constexpr (CPL == 4) {
        ushort4 a0 = *(const ushort4*)(Xc + (size_t)n_0 * F);
        ushort4 a1 = *(const ushort4*)(Xc + (size_t)n_1 * F);
        ushort4 a2 = *(const ushort4*)(Xc + (size_t)n_2 * F);
        ushort4 a3 = *(const ushort4*)(Xc + (size_t)n_3 * F);
        acc[0] += d0 * b2f(a0.x) + d1 * b2f(a1.x) + d2 * b2f(a2.x) + d3 * b2f(a3.x);
        acc[1] += d0 * b2f(a0.y) + d1 * b2f(a1.y) + d2 * b2f(a2.y) + d3 * b2f(a3.y);
        acc[2] += d0 * b2f(a0.z) + d1 * b2f(a1.z) + d2 * b2f(a2.z) + d3 * b2f(a3.z);
        acc[3] += d0 * b2f(a0.w) + d1 * b2f(a1.w) + d2 * b2f(a2.w) + d3 * b2f(a3.w);
      } else {
        ushort2 a0 = *(const ushort2*)(Xc + (size_t)n_0 * F);
        ushort2 a1 = *(const ushort2*)(Xc + (size_t)n_1 * F);
        ushort2 a2 = *(const ushort2*)(Xc + (size_t)n_2 * F);
        ushort2 a3 = *(const ushort2*)(Xc + (size_t)n_3 * F);
        acc[0] += d0 * b2f(a0.x) + d1 * b2f(a1.x) + d2 * b2f(a2.x) + d3 * b2f(a3.x);
        acc[1] += d0 * b2f(a0.y) + d1 * b2f(a1.y) + d2 * b2f(a2.y) + d3 * b2f(a3.y);
      }
    }
  }
  float rwr = rel_w(rel, r);
  float de2 = 1.0f / (rwr * decnt[r * EE + e] + 1e-8f);
  unsigned short* dst = out + ((size_t)r * EE + e) * F + lane * CPL;
  if constexpr (CPL == 4) {
    ushort4 o;
    o.x = f2b(acc[0] * de2); o.y = f2b(acc[1] * de2);
    o.z = f2b(acc[2] * de2); o.w = f2b(acc[3] * de2);
    *(ushort4*)dst = o;
  } else {
    ushort2 o;
    o.x = f2b(acc[0] * de2); o.y = f2b(acc[1] * de2);
    *(ushort2*)dst = o;
  }
}

// ---------------- SpMM-N: out[n] = dvs[r][n] * sum_{e:bit} T2[r][e][f] ----------------
template <int CPL>
__global__ void k_spmm_n(const unsigned short* __restrict__ T2,
                         const unsigned long long* __restrict__ mask,
                         const float* __restrict__ dvs,
                         unsigned short* __restrict__ out, long rstride, int ldo) {
  const int F = CPL * 64;
  int wid = threadIdx.x >> 6, lane = threadIdx.x & 63;
  int n = (blockIdx.x << 2) | wid;
  int r = blockIdx.y;
  const unsigned long long* wrow = mask + ((size_t)r * NN + n) * (EE / 64);
  const unsigned short* Tc = T2 + (size_t)r * EE * F + lane * CPL;
  float acc[CPL];
#pragma unroll
  for (int i = 0; i < CPL; i++) acc[i] = 0.f;
  for (int c = 0; c < EE / 64; c++) {
    unsigned long long m = wrow[c];
    int e0 = c << 6;
    while (m) {
      int j0 = __ffsll((long long)m) - 1; m &= m - 1;
      int j1 = j0, j2 = j0, j3 = j0;
      float w1 = 0.f, w2 = 0.f, w3 = 0.f;
      if (m) { j1 = __ffsll((long long)m) - 1; m &= m - 1; w1 = 1.f; }
      if (m) { j2 = __ffsll((long long)m) - 1; m &= m - 1; w2 = 1.f; }
      if (m) { j3 = __ffsll((long long)m) - 1; m &= m - 1; w3 = 1.f; }
      int e_0 = e0 + j0, e_1 = e0 + j1, e_2 = e0 + j2, e_3 = e0 + j3;
      if constexpr (CPL == 4) {
        ushort4 a0 = *(const ushort4*)(Tc + (size_t)e_0 * F);
        ushort4 a1 = *(const ushort4*)(Tc + (size_t)e_1 * F);
        ushort4 a2 = *(const ushort4*)(Tc + (size_t)e_2 * F);
        ushort4 a3 = *(const ushort4*)(Tc + (size_t)e_3 * F);
        acc[0] += b2f(a0.x) + w1 * b2f(a1.x) + w2 * b2f(a2.x) + w3 * b2f(a3.x);
        acc[1] += b2f(a0.y) + w1 * b2f(a1.y) + w2 * b2f(a2.y) + w3 * b2f(a3.y);
        acc[2] += b2f(a0.z) + w1 * b2f(a1.z) + w2 * b2f(a2.z) + w3 * b2f(a3.z);
        acc[3] += b2f(a0.w) + w1 * b2f(a1.w) + w2 * b2f(a2.w) + w3 * b2f(a3.w);
      } else {
        ushort2 a0 = *(const ushort2*)(Tc + (size_t)e_0 * F);
        ushort2 a1 = *(const ushort2*)(Tc + (size_t)e_1 * F);
        ushort2 a2 = *(const ushort2*)(Tc + (size_t)e_2 * F);
        ushort2 a3 = *(const ushort2*)(Tc + (size_t)e_3 * F);
        acc[0] += b2f(a0.x) + w1 * b2f(a1.x) + w2 * b2f(a2.x) + w3 * b2f(a3.x);
        acc[1] += b2f(a0.y) + w1 * b2f(a1.y) + w2 * b2f(a2.y) + w3 * b2f(a3.y);
      }
    }
  }
  float dvn = dvs[r * NN + n];
  unsigned short* dst = out + (size_t)r * rstride + (size_t)n * ldo + lane * CPL;
  if constexpr (CPL == 4) {
    ushort4 o;
    o.x = f2b(acc[0] * dvn); o.y = f2b(acc[1] * dvn);
    o.z = f2b(acc[2] * dvn); o.w = f2b(acc[3] * dvn);
    *(ushort4*)dst = o;
  } else {
    ushort2 o;
    o.x = f2b(acc[0] * dvn); o.y = f2b(acc[1] * dvn);
    *(ushort2*)dst = o;
  }
}

// ---------------- MFMA GEMM, 128x128 tile, BK=64, async staging, bf16 stores ----------------
// z = zr*SK + kz. P[z][c_ps] bf16 (partials when SK>1 or rel-summed later; direct outputs when not).
__global__ __launch_bounds__(256) void k_gemm3(
    const unsigned short* __restrict__ A, const unsigned short* __restrict__ BT,
    int K, int SK, int lda, int ldb, long a_rs, long b_rs,
    unsigned short* __restrict__ P, long c_ps, int ldc) {
  __shared__ unsigned short Al[8 * 1040];
  __shared__ unsigned short Bl[8 * 1040];
  int tid = threadIdx.x, wid = tid >> 6, lane = tid & 63;
  int m0 = blockIdx.x << 7, n0 = blockIdx.y << 7;
  int z = blockIdx.z, zr = z / SK, kz = z - zr * SK;
  int Kc = K / SK;
  const unsigned short* Ab = A + (size_t)zr * a_rs + (size_t)m0 * lda + (size_t)kz * Kc;
  const unsigned short* Bb = BT + (size_t)zr * b_rs + (size_t)n0 * ldb + (size_t)kz * Kc;
  int wm = (wid >> 1) << 6, wn = (wid & 1) << 6;
  int fm = lane & 15, quad = lane >> 4;
  floatx4 acc[4][4];
#pragma unroll
  for (int i = 0; i < 4; i++)
#pragma unroll
    for (int j = 0; j < 4; j++) acc[i][j] = (floatx4){0.f, 0.f, 0.f, 0.f};
  for (int k0 = 0; k0 < Kc; k0 += 64) {
#pragma unroll
    for (int t = 0; t < 4; t++) {
      int idx = (t << 2) | wid;
      int kg = idx >> 1, half = (idx & 1) << 6;
      async16(Ab + (size_t)(half + lane) * lda + k0 + kg * 8, &Al[kg * 1040 + half * 8 + lane * 8]);
      async16(Bb + (size_t)(half + lane) * ldb + k0 + kg * 8, &Bl[kg * 1040 + half * 8 + lane * 8]);
    }
    __syncthreads();
#pragma unroll
    for (int ks = 0; ks < 2; ks++) {
      int kgb = ((ks << 2) | quad) * 1040;
      bf16x8 a[4], b[4];
#pragma unroll
      for (int i = 0; i < 4; i++) {
        a[i] = *(const bf16x8*)&Al[kgb + (wm + i * 16 + fm) * 8];
        b[i] = *(const bf16x8*)&Bl[kgb + (wn + i * 16 + fm) * 8];
      }
#pragma unroll
      for (int i = 0; i < 4; i++)
#pragma unroll
        for (int j = 0; j < 4; j++)
          acc[i][j] = __builtin_amdgcn_mfma_f32_16x16x32_bf16(a[i], b[j], acc[i][j], 0, 0, 0);
    }
    __syncthreads();
  }
  unsigned short* Cb = P + (size_t)z * c_ps;
#pragma unroll
  for (int mi = 0; mi < 4; mi++)
#pragma unroll
    for (int ni = 0; ni < 4; ni++)
#pragma unroll
      for (int v = 0; v < 4; v++) {
        int row = m0 + wm + mi * 16 + quad * 4 + v;
        int col = n0 + wn + ni * 16 + fm;
        Cb[(size_t)row * ldc + col] = f2b(acc[mi][ni][v]);
      }
}

// ---- reduce Z bf16 partials of [NN][HDD] -> convout f32 + fused BN column stats ----
__global__ void k_redstats(const unsigned short* __restrict__ P, float* __restrict__ out,
                           float* __restrict__ cs, float* __restrict__ cs2, int Z) {
  __shared__ float sm[2][8][256];
  int cg = (threadIdx.x & 31) << 3;
  int rowt = threadIdx.x >> 5;
  int r0 = blockIdx.x * 32;
  float s[8] = {0, 0, 0, 0, 0, 0, 0, 0}, s2[8] = {0, 0, 0, 0, 0, 0, 0, 0};
  for (int j = 0; j < 4; j++) {
    long idx = (long)(r0 + rowt * 4 + j) * HDD + cg;
    float acc[8] = {0, 0, 0, 0, 0, 0, 0, 0};
    for (int z = 0; z < Z; z++) {
      const unsigned short* p = P + (size_t)z * ((long)NN * HDD) + idx;
      ushort4 a = *(const ushort4*)p;
      ushort4 b = *(const ushort4*)(p + 4);
      acc[0] += b2f(a.x); acc[1] += b2f(a.y); acc[2] += b2f(a.z); acc[3] += b2f(a.w);
      acc[4] += b2f(b.x); acc[5] += b2f(b.y); acc[6] += b2f(b.z); acc[7] += b2f(b.w);
    }
    float4 o0 = {acc[0], acc[1], acc[2], acc[3]};
    float4 o1 = {acc[4], acc[5], acc[6], acc[7]};
    *(float4*)(out + idx) = o0;
    *(float4*)(out + idx + 4) = o1;
#pragma unroll
    for (int i = 0; i < 8; i++) { s[i] += acc[i]; s2[i] += acc[i] * acc[i]; }
  }
#pragma unroll
  for (int i = 0; i < 8; i++) { sm[0][rowt][cg + i] = s[i]; sm[1][rowt][cg + i] = s2[i]; }
  __syncthreads();
  int c = threadIdx.x;
  float a0 = 0, a1 = 0;
#pragma unroll
  for (int t = 0; t < 8; t++) { a0 += sm[0][t][c]; a1 += sm[1][t][c]; }
  atomicAdd(&cs[c], a0);
  atomicAdd(&cs2[c], a1);
}

// ---- final: d_out = X + b3 + sum_Z bf16 partials [Z][NN][FF] ----
__global__ void k_red_out(const unsigned short* __restrict__ P, const float* __restrict__ X,
                          const float* __restrict__ b3, float* __restrict__ out, int Z) {
  long i = ((long)blockIdx.x * 256 + threadIdx.x) * 4;
  int f = (int)(i & 127);
  float4 s = *(const float4*)(X + i);
  s.x += b3[f]; s.y += b3[f + 1]; s.z += b3[f + 2]; s.w += b3[f + 3];
  for (int z = 0; z < Z; z++) {
    ushort4 v = *(const ushort4*)(P + (size_t)z * (NN * FF) + i);
    s.x += b2f(v.x); s.y += b2f(v.y); s.z += b2f(v.z); s.w += b2f(v.w);
  }
  *(float4*)(out + i) = s;
}

// ---- BN (batch stats) -> LN -> ELU -> bf16 [NN][HDD] ----
__global__ void k_bnlnelu(const float* __restrict__ x, const float* __restrict__ cs, const float* __restrict__ cs2,
                          const float* __restrict__ bg, const float* __restrict__ bb,
                          const float* __restrict__ lg, const float* __restrict__ lb,
                          unsigned short* __restrict__ out) {
  int wid = threadIdx.x >> 6, lane = threadIdx.x & 63;
  int n = blockIdx.x * 4 + wid;
  float y[4];
  float m = 0.f;
#pragma unroll
  for (int j = 0; j < 4; j++) {
    int c = lane + 64 * j;
    float mu = cs[c] * (1.0f / NN);
    float var = cs2[c] * (1.0f / NN) - mu * mu;
    float xv = x[(size_t)n * HDD + c];
    y[j] = (xv - mu) * rsqrtf(var + 1e-5f) * bg[c] + bb[c];
    m += y[j];
  }
  for (int off = 32; off; off >>= 1) m += __shfl_down(m, off);
  m = __shfl(m, 0) * (1.0f / HDD);
  float var = 0.f;
#pragma unroll
  for (int j = 0; j < 4; j++) { float d = y[j] - m; var += d * d; }
  for (int off = 32; off; off >>= 1) var += __shfl_down(var, off);
  var = __shfl(var, 0) * (1.0f / HDD);
  float inv = rsqrtf(var + 1e-5f);
#pragma unroll
  for (int j = 0; j < 4; j++) {
    int c = lane + 64 * j;
    float z = (y[j] - m) * inv * lg[c] + lb[c];
    z = z > 0.f ? z : expm1f(z);
    out[(size_t)n * HDD + c] = f2b(z);
  }
}

extern "C" void kernel_launch(void* const* d_in, const int* in_sizes, int n_in,
                              void* d_out, int out_size, void* d_ws, size_t ws_size,
                              hipStream_t stream) {
  const float* X   = (const float*)d_in[0];
  const float* H   = (const float*)d_in[1];
  const float* W1  = (const float*)d_in[2];
  const float* W2  = (const float*)d_in[3];
  const float* W3  = (const float*)d_in[4];
  const float* imp = (const float*)d_in[5];
  const float* b3  = (const float*)d_in[8];
  const float* bng = (const float*)d_in[9];
  const float* bnb = (const float*)d_in[10];
  const float* lng = (const float*)d_in[11];
  const float* lnb = (const float*)d_in[12];
  const float* rel = (const float*)d_in[13];
  (void)in_sizes; (void)n_in; (void)out_size; (void)ws_size;

  char* w = (char*)d_ws;
  size_t off = 0;
  auto alloc = [&](size_t bytes) -> void* {
    void* p = w + off;
    off += (bytes + 255) & ~(size_t)255;
    return p;
  };
  float* dvs  = (float*)alloc((size_t)RR * NN * 4);
  float* de   = (float*)alloc((size_t)RR * EE * 4);           // raw column counts
  float* cs   = (float*)alloc(2 * HDD * 4);                   // [cs | cs2]
  unsigned long long* mask  = (unsigned long long*)alloc((size_t)RR * NN * (EE / 64) * 8);  // 4MB
  unsigned long long* maskT = (unsigned long long*)alloc((size_t)RR * EE * (NN / 64) * 8);  // 4MB
  unsigned short* Xf   = (unsigned short*)alloc((size_t)NN * FF * 2);          // 1MB  X bf16
  unsigned short* t1   = (unsigned short*)alloc((size_t)RR * EE * HDD * 2);    // 4MB  (t1/t2/t3)
  unsigned short* Hcat = (unsigned short*)alloc((size_t)NN * RR * FF * 2);     // 4MB
  unsigned short* Hn   = (unsigned short*)alloc((size_t)RR * NN * HDD * 2);    // 8MB
  unsigned short* bufP = (unsigned short*)alloc((size_t)4 * NN * HDD * 2);     // 8MB partials
  unsigned short* yb   = (unsigned short*)alloc((size_t)RR * NN * FF * 2);     // 4MB
  unsigned short* P3   = (unsigned short*)alloc((size_t)RR * NN * FF * 2);     // 4MB
  float* convout = (float*)alloc((size_t)NN * HDD * 4);                        // 4MB
  unsigned short* Xb = (unsigned short*)alloc((size_t)NN * HDD * 2);           // 2MB
  unsigned short* W1catT = (unsigned short*)alloc((size_t)RR * FF * HDD * 2);
  unsigned short* W2T    = (unsigned short*)alloc((size_t)RR * HDD * HDD * 2);
  unsigned short* W3T    = (unsigned short*)alloc((size_t)RR * HDD * FF * 2);

  // ---- prep ----
  k_cvt<<<(NN * FF) / 1024, 256, 0, stream>>>(X, Xf);
  k_dvmask<<<(RR * NN) / 4, 256, 0, stream>>>(H, rel, dvs, mask);
  hipMemsetAsync(de, 0, (size_t)RR * EE * 4, stream);
  k_de_pop<<<dim3(EE / 64, NN / 256, RR), 256, 0, stream>>>(mask, de, maskT);
  k_wprep<<<(RR * FF * HDD + RR * HDD * HDD + RR * HDD * FF) / 256, 256, 0, stream>>>(
      W1, W2, W3, imp, W1catT, W2T, W3T);

  // ---- layer 1 (128 -> 256): conv = [dvs*B(de2*(B^T(dvs*X)))] @ W1cat ----
  k_spmm_t<2><<<dim3(EE / 4, RR), 256, 0, stream>>>(Xf, 0, maskT, dvs, de, rel, t1);
  k_spmm_n<2><<<dim3(NN / 4, RR), 256, 0, stream>>>(t1, mask, dvs, Hcat, (long)FF, RR * FF);
  // convout = Hcat @ W1cat   M=4096,N=256,K=512, SK=4 -> 256 blocks
  k_gemm3<<<dim3(NN / 128, HDD / 128, 4), 256, 0, stream>>>(
      Hcat, W1catT, RR * FF, 4, RR * FF, RR * FF, 0, 0, bufP, (long)NN * HDD, HDD);
  hipMemsetAsync(cs, 0, 2 * HDD * 4, stream);
  k_redstats<<<NN / 32, 256, 0, stream>>>(bufP, convout, cs, cs + HDD, 4);
  k_bnlnelu<<<NN / 4, 256, 0, stream>>>(convout, cs, cs + HDD, bng, bnb, lng, lnb, Xb);

  // ---- layer 2 (256 -> 256): conv = sum_r [dvs*B(de2*(B^T(dvs*h)))] @ W2_r ----
  k_spmm_t<4><<<dim3(EE / 4, RR), 256, 0, stream>>>(Xb, 0, maskT, dvs, de, rel, t1);
  k_spmm_n<4><<<dim3(NN / 4, RR), 256, 0, stream>>>(t1, mask, dvs, Hn, (long)NN * HDD, HDD);
  // bufP[r] = Hn[r] @ W2T[r]   M=4096,N=256,K=256, SK=1, z=r -> 256 blocks
  k_gemm3<<<dim3(NN / 128, HDD / 128, RR), 256, 0, stream>>>(
      Hn, W2T, HDD, 1, HDD, HDD, (long)NN * HDD, (long)HDD * HDD, bufP, (long)NN * HDD, HDD);
  hipMemsetAsync(cs, 0, 2 * HDD * 4, stream);
  k_redstats<<<NN / 32, 256, 0, stream>>>(bufP, convout, cs, cs + HDD, 4);
  k_bnlnelu<<<NN / 4, 256, 0, stream>>>(convout, cs, cs + HDD, bng + HDD, bnb + HDD, lng + HDD, lnb + HDD, Xb);

  // ---- layer 3 (256 -> 128), W3 applied FIRST: y_r = h @ W3_r, out = X + b3 + sum_r dvs*B(de2*(B^T(dvs*y_r))) ----
  // yb[r] = Xb @ W3T[r]   M=4096,N=128,K=256, SK=1, z=r -> 128 blocks (direct bf16 output)
  k_gemm3<<<dim3(NN / 128, 1, RR), 256, 0, stream>>>(
      Xb, W3T, HDD, 1, HDD, HDD, 0, (long)FF * HDD, yb, (long)NN * FF, FF);
  k_spmm_t<2><<<dim3(EE / 4, RR), 256, 0, stream>>>(yb, (long)NN * FF, maskT, dvs, de, rel, t1);
  k_spmm_n<2><<<dim3(NN / 4, RR), 256, 0, stream>>>(t1, mask, dvs, P3, (long)NN * FF, FF);
  k_red_out<<<(NN * FF) / 1024, 256, 0, stream>>>(P3, X, b3, (float*)d_out, RR);
}

// Round 9
// 506.085 us; speedup vs baseline: 1.6663x; 1.6663x over previous
//
#include <hip/hip_runtime.h>
#include <hip/hip_bf16.h>

#define NN 4096
#define EE 2048
#define RR 4
#define FF 128
#define HDD 256

typedef __attribute__((ext_vector_type(4))) float floatx4;
typedef __attribute__((ext_vector_type(8))) __bf16 bf16x8;

#define AS1 __attribute__((address_space(1)))
#define AS3 __attribute__((address_space(3)))

__device__ __forceinline__ void async16(const void* g, void* l) {
  // global -> LDS direct copy, 16B per lane; LDS dest = wave-uniform base + lane*16
  __builtin_amdgcn_global_load_lds((const AS1 void*)(unsigned long long)(g),
                                   (AS3 void*)(unsigned int)(unsigned long long)(l),
                                   16, 0, 0);
}

__device__ inline unsigned short f2b(float x) {
  unsigned int u = __float_as_uint(x);
  unsigned int r = u + 0x7fffu + ((u >> 16) & 1u);
  return (unsigned short)(r >> 16);
}
__device__ inline float b2f(unsigned short u) { return __uint_as_float((unsigned int)u << 16); }

__device__ inline float rel_w(const float* rel, int r) {
  float m = fmaxf(fmaxf(rel[0], rel[1]), fmaxf(rel[2], rel[3]));
  float s = 0.f;
#pragma unroll
  for (int i = 0; i < RR; i++) s += expf(rel[i] - m);
  return expf(rel[r] - m) / s;
}

// ---- single pass over H: row sums -> dvs[r][n] = rw*rsqrt(rw*sum+eps), plus 0/1 bitmask ----
__global__ void k_dvmask(const float* __restrict__ H, const float* __restrict__ rel,
                         float* __restrict__ dvs, unsigned long long* __restrict__ mask) {
  int wave = (blockIdx.x << 2) | (threadIdx.x >> 6);  // = r*NN + n
  int lane = threadIdx.x & 63;
  int r = wave >> 12;
  const float* row = H + (size_t)wave * EE;
  unsigned long long* mrow = mask + (size_t)wave * (EE / 64);
  float s = 0.f;
  for (int j = 0; j < EE / 64; j++) {
    float h = row[j * 64 + lane];
    s += h;
    unsigned long long m = __ballot(h != 0.0f);
    if (lane == 0) mrow[j] = m;
  }
  for (int off = 32; off; off >>= 1) s += __shfl_down(s, off);
  if (lane == 0) {
    float rwr = rel_w(rel, r);
    dvs[wave] = rwr * rsqrtf(rwr * s + 1e-8f);
  }
}

// ---- column counts via ballot bit-transpose ----
__global__ void k_de_pop(const unsigned long long* __restrict__ mask, float* __restrict__ de_acc) {
  int wid = threadIdx.x >> 6, lane = threadIdx.x & 63;
  int wcol = blockIdx.x, r = blockIdx.z;
  int n0 = (blockIdx.y << 8) + (wid << 6);
  unsigned long long w = mask[(size_t)(r * NN + n0 + lane) * (EE / 64) + wcol];
  float cnt = 0.f;
#pragma unroll
  for (int b = 0; b < 64; b++) {
    unsigned long long m = __ballot(((w >> b) & 1ULL) != 0);
    if (lane == b) cnt = (float)__popcll(m);
  }
  atomicAdd(&de_acc[r * EE + (wcol << 6) + lane], cnt);
}

// ---- build theta[r][n][e] bf16 and thetaT[r][e][n]; de rsqrt fused ----
__global__ void k_build_theta_bits(const unsigned long long* __restrict__ mask,
                                   const float* __restrict__ dvs, const float* __restrict__ decnt,
                                   const float* __restrict__ rel,
                                   unsigned short* __restrict__ theta, unsigned short* __restrict__ thetaT) {
  __shared__ unsigned short tile[64][65];
  int r = blockIdx.z;
  int e0 = blockIdx.x * 64, n0 = blockIdx.y * 64;
  int tr = threadIdx.x >> 4, tc = threadIdx.x & 15;
  float rwr = rel_w(rel, r);
  float de0 = rsqrtf(rwr * decnt[r * EE + e0 + tc * 4 + 0] + 1e-8f);
  float de1 = rsqrtf(rwr * decnt[r * EE + e0 + tc * 4 + 1] + 1e-8f);
  float de2 = rsqrtf(rwr * decnt[r * EE + e0 + tc * 4 + 2] + 1e-8f);
  float de3 = rsqrtf(rwr * decnt[r * EE + e0 + tc * 4 + 3] + 1e-8f);
  int wcol = e0 >> 6;
#pragma unroll
  for (int i = 0; i < 4; i++) {
    int n = n0 + tr + 16 * i;
    unsigned long long w = mask[((size_t)r * NN + n) * (EE / 64) + wcol];
    float d = dvs[r * NN + n];
    unsigned short b0 = ((w >> (tc * 4 + 0)) & 1) ? f2b(d * de0) : 0;
    unsigned short b1 = ((w >> (tc * 4 + 1)) & 1) ? f2b(d * de1) : 0;
    unsigned short b2 = ((w >> (tc * 4 + 2)) & 1) ? f2b(d * de2) : 0;
    unsigned short b3 = ((w >> (tc * 4 + 3)) & 1) ? f2b(d * de3) : 0;
    ushort4 o; o.x = b0; o.y = b1; o.z = b2; o.w = b3;
    *(ushort4*)(theta + ((size_t)r * NN + n) * EE + e0 + tc * 4) = o;
    tile[tr + 16 * i][tc * 4 + 0] = b0;
    tile[tr + 16 * i][tc * 4 + 1] = b1;
    tile[tr + 16 * i][tc * 4 + 2] = b2;
    tile[tr + 16 * i][tc * 4 + 3] = b3;
  }
  __syncthreads();
#pragma unroll
  for (int i = 0; i < 4; i++) {
    int e = e0 + tr + 16 * i;
    ushort4 o;
    o.x = tile[tc * 4 + 0][tr + 16 * i];
    o.y = tile[tc * 4 + 1][tr + 16 * i];
    o.z = tile[tc * 4 + 2][tr + 16 * i];
    o.w = tile[tc * 4 + 3][tr + 16 * i];
    *(ushort4*)(thetaT + ((size_t)r * EE + e) * NN + n0 + tc * 4) = o;
  }
}

// ---- f32 [M][C] -> bf16 [C][M] (transpose+convert) ----
__global__ void k_cvtT(const float* __restrict__ src, unsigned short* __restrict__ dst, int M, int C) {
  __shared__ unsigned short tile[64][65];
  int c0 = blockIdx.x * 64, m0 = blockIdx.y * 64;
  int tr = threadIdx.x >> 4, tc = threadIdx.x & 15;
#pragma unroll
  for (int i = 0; i < 4; i++) {
    int m = m0 + tr + 16 * i;
    float4 v = *(const float4*)(src + (size_t)m * C + c0 + tc * 4);
    tile[tr + 16 * i][tc * 4 + 0] = f2b(v.x);
    tile[tr + 16 * i][tc * 4 + 1] = f2b(v.y);
    tile[tr + 16 * i][tc * 4 + 2] = f2b(v.z);
    tile[tr + 16 * i][tc * 4 + 3] = f2b(v.w);
  }
  __syncthreads();
#pragma unroll
  for (int i = 0; i < 4; i++) {
    int c = c0 + tr + 16 * i;
    ushort4 v;
    v.x = tile[tc * 4 + 0][tr + 16 * i];
    v.y = tile[tc * 4 + 1][tr + 16 * i];
    v.z = tile[tc * 4 + 2][tr + 16 * i];
    v.w = tile[tc * 4 + 3][tr + 16 * i];
    *(ushort4*)(dst + (size_t)c * M + m0 + tc * 4) = v;
  }
}

// ---- bf16 [M][C] -> bf16 [C][M] ----
__global__ void k_trz(const unsigned short* __restrict__ src, unsigned short* __restrict__ dst, int M, int C) {
  __shared__ unsigned short tile[64][65];
  int c0 = blockIdx.x * 64, m0 = blockIdx.y * 64;
  int tr = threadIdx.x >> 4, tc = threadIdx.x & 15;
#pragma unroll
  for (int i = 0; i < 4; i++) {
    int m = m0 + tr + 16 * i;
    ushort4 v = *(const ushort4*)(src + (size_t)m * C + c0 + tc * 4);
    tile[tr + 16 * i][tc * 4 + 0] = v.x;
    tile[tr + 16 * i][tc * 4 + 1] = v.y;
    tile[tr + 16 * i][tc * 4 + 2] = v.z;
    tile[tr + 16 * i][tc * 4 + 3] = v.w;
  }
  __syncthreads();
#pragma unroll
  for (int i = 0; i < 4; i++) {
    int c = c0 + tr + 16 * i;
    ushort4 v;
    v.x = tile[tc * 4 + 0][tr + 16 * i];
    v.y = tile[tc * 4 + 1][tr + 16 * i];
    v.z = tile[tc * 4 + 2][tr + 16 * i];
    v.w = tile[tc * 4 + 3][tr + 16 * i];
    *(ushort4*)(dst + (size_t)c * M + m0 + tc * 4) = v;
  }
}

// ---- all three weight transforms in ONE launch ----
__global__ void k_wprep(const float* __restrict__ W1, const float* __restrict__ W2,
                        const float* __restrict__ W3, const float* __restrict__ imp,
                        unsigned short* __restrict__ W1catT, unsigned short* __restrict__ W2T,
                        unsigned short* __restrict__ W3T) {
  int idx = blockIdx.x * 256 + threadIdx.x;
  if (idx < RR * FF * HDD) {
    int o = idx % HDD, f = (idx / HDD) % FF, r = idx / (HDD * FF);
    float sg = 1.0f / (1.0f + expf(-imp[r]));
    W1catT[(size_t)o * (RR * FF) + r * FF + f] = f2b(sg * W1[((size_t)r * FF + f) * HDD + o]);
  } else if (idx < RR * FF * HDD + RR * HDD * HDD) {
    int j = idx - RR * FF * HDD;
    int c = j % HDD, o = (j / HDD) % HDD, r = j / (HDD * HDD);
    float sg = 1.0f / (1.0f + expf(-imp[RR + r]));
    W2T[j] = f2b(sg * W2[((size_t)r * HDD + c) * HDD + o]);
  } else {
    int j = idx - RR * FF * HDD - RR * HDD * HDD;
    int c = j % HDD, o = (j / HDD) % FF, r = j / (HDD * FF);
    float sg = 1.0f / (1.0f + expf(-imp[2 * RR + r]));
    W3T[j] = f2b(sg * W3[((size_t)r * HDD + c) * FF + o]);
  }
}

// ---------------- MFMA GEMM, 128x128 tile, BK=64, COALESCED async staging (XOR swizzle) ----------------
// Staging: 8 lanes cover one row's 64 k-elems (contiguous 128B), 8 rows/instr, chunk c^r8 swizzle.
// LDS layout: [row][kchunk c] elems, cell (R, c) holds global kchunk c^(R&7). 16KB per operand.
// z = zr*SK + kz. P[z][c_ps] bf16, plain stores.
__global__ __launch_bounds__(256) void k_gemm3(
    const unsigned short* __restrict__ A, const unsigned short* __restrict__ BT,
    int K, int SK, int lda, int ldb, long a_rs, long b_rs,
    unsigned short* __restrict__ P, long c_ps, int ldc) {
  __shared__ unsigned short Al[128 * 64];
  __shared__ unsigned short Bl[128 * 64];
  int tid = threadIdx.x, wid = tid >> 6, lane = tid & 63;
  int m0 = blockIdx.x << 7, n0 = blockIdx.y << 7;
  int z = blockIdx.z, zr = z / SK, kz = z - zr * SK;
  int Kc = K / SK;
  int r8 = lane >> 3, c8 = lane & 7;
  int swz = ((c8 ^ r8) << 3);               // element offset of this lane's 16B chunk within the row
  const unsigned short* Ab = A + (size_t)zr * a_rs + (size_t)m0 * lda + (size_t)kz * Kc;
  const unsigned short* Bb = BT + (size_t)zr * b_rs + (size_t)n0 * ldb + (size_t)kz * Kc;
  int wm = (wid >> 1) << 6, wn = (wid & 1) << 6;
  int fm = lane & 15, quad = lane >> 4;
  int f7 = fm & 7;
  floatx4 acc[4][4];
#pragma unroll
  for (int i = 0; i < 4; i++)
#pragma unroll
    for (int j = 0; j < 4; j++) acc[i][j] = (floatx4){0.f, 0.f, 0.f, 0.f};
  for (int k0 = 0; k0 < Kc; k0 += 64) {
#pragma unroll
    for (int t = 0; t < 4; t++) {
      int rbase = (wid << 5) + (t << 3);    // 0..120, wave covers 32 rows in 4 instrs
      int row = rbase + r8;
      async16(Ab + (size_t)row * lda + k0 + swz, &Al[rbase * 64 + lane * 8]);
      async16(Bb + (size_t)row * ldb + k0 + swz, &Bl[rbase * 64 + lane * 8]);
    }
    __syncthreads();  // vmcnt(0) drain before s_barrier -> LDS writes visible
#pragma unroll
    for (int ks = 0; ks < 2; ks++) {
      int kg = (ks << 2) | quad;
      int ko = ((kg ^ f7) << 3);
      bf16x8 a[4], b[4];
#pragma unroll
      for (int i = 0; i < 4; i++) {
        a[i] = *(const bf16x8*)&Al[(wm + i * 16 + fm) * 64 + ko];
        b[i] = *(const bf16x8*)&Bl[(wn + i * 16 + fm) * 64 + ko];
      }
#pragma unroll
      for (int i = 0; i < 4; i++)
#pragma unroll
        for (int j = 0; j < 4; j++)
          acc[i][j] = __builtin_amdgcn_mfma_f32_16x16x32_bf16(a[i], b[j], acc[i][j], 0, 0, 0);
    }
    __syncthreads();
  }
  unsigned short* Cb = P + (size_t)z * c_ps;
#pragma unroll
  for (int mi = 0; mi < 4; mi++)
#pragma unroll
    for (int ni = 0; ni < 4; ni++)
#pragma unroll
      for (int v = 0; v < 4; v++) {
        int row = m0 + wm + mi * 16 + quad * 4 + v;
        int col = n0 + wn + ni * 16 + fm;
        Cb[(size_t)row * ldc + col] = f2b(acc[mi][ni][v]);
      }
}

// ---- reduce SK bf16 partials per zr -> bf16 out[zr][region] ----
__global__ void k_red_b(const unsigned short* __restrict__ P, unsigned short* __restrict__ out,
                        int SK, long region) {
  long i = ((long)blockIdx.x * 256 + threadIdx.x) * 8;
  int zr = blockIdx.y;
  const unsigned short* p = P + (size_t)zr * SK * region + i;
  float s[8] = {0, 0, 0, 0, 0, 0, 0, 0};
  for (int k = 0; k < SK; k++) {
    const unsigned short* q = p + (size_t)k * region;
    ushort4 a = *(const ushort4*)q;
    ushort4 b = *(const ushort4*)(q + 4);
    s[0] += b2f(a.x); s[1] += b2f(a.y); s[2] += b2f(a.z); s[3] += b2f(a.w);
    s[4] += b2f(b.x); s[5] += b2f(b.y); s[6] += b2f(b.z); s[7] += b2f(b.w);
  }
  ushort4 o0, o1;
  o0.x = f2b(s[0]); o0.y = f2b(s[1]); o0.z = f2b(s[2]); o0.w = f2b(s[3]);
  o1.x = f2b(s[4]); o1.y = f2b(s[5]); o1.z = f2b(s[6]); o1.w = f2b(s[7]);
  unsigned short* d = out + (size_t)zr * region + i;
  *(ushort4*)d = o0;
  *(ushort4*)(d + 4) = o1;
}

// ---- reduce SK bf16 partials of [M][C] per zr AND transpose -> bf16 outT[zr][C][M] ----
__global__ void k_redT_b(const unsigned short* __restrict__ P, unsigned short* __restrict__ outT,
                         int SK, int M, int C) {
  __shared__ unsigned short tile[64][65];
  int zr = blockIdx.z;
  long region = (long)M * C;
  const unsigned short* p0 = P + (size_t)zr * SK * region;
  int c0 = blockIdx.x * 64, m0 = blockIdx.y * 64;
  int tr = threadIdx.x >> 4, tc = threadIdx.x & 15;
#pragma unroll
  for (int i = 0; i < 4; i++) {
    int m = m0 + tr + 16 * i;
    const unsigned short* p = p0 + (size_t)m * C + c0 + tc * 4;
    float s0 = 0, s1 = 0, s2 = 0, s3 = 0;
    for (int k = 0; k < SK; k++) {
      ushort4 v = *(const ushort4*)(p + (size_t)k * region);
      s0 += b2f(v.x); s1 += b2f(v.y); s2 += b2f(v.z); s3 += b2f(v.w);
    }
    tile[tr + 16 * i][tc * 4 + 0] = f2b(s0);
    tile[tr + 16 * i][tc * 4 + 1] = f2b(s1);
    tile[tr + 16 * i][tc * 4 + 2] = f2b(s2);
    tile[tr + 16 * i][tc * 4 + 3] = f2b(s3);
  }
  __syncthreads();
  unsigned short* d = outT + (size_t)zr * region;
#pragma unroll
  for (int i = 0; i < 4; i++) {
    int c = c0 + tr + 16 * i;
    ushort4 v;
    v.x = tile[tc * 4 + 0][tr + 16 * i];
    v.y = tile[tc * 4 + 1][tr + 16 * i];
    v.z = tile[tc * 4 + 2][tr + 16 * i];
    v.w = tile[tc * 4 + 3][tr + 16 * i];
    *(ushort4*)(d + (size_t)c * M + m0 + tc * 4) = v;
  }
}

// ---- reduce SK bf16 partials per r of [NN][FF] -> Hcat[n][r*FF+f] bf16 ----
__global__ void k_red_hcatb(const unsigned short* __restrict__ P, unsigned short* __restrict__ out, int SK) {
  long i = ((long)blockIdx.x * 256 + threadIdx.x) * 8;
  int r = blockIdx.y;
  const unsigned short* p = P + (size_t)r * SK * (NN * FF) + i;
  float s[8] = {0, 0, 0, 0, 0, 0, 0, 0};
  for (int k = 0; k < SK; k++) {
    const unsigned short* q = p + (size_t)k * (NN * FF);
    ushort4 a = *(const ushort4*)q;
    ushort4 b = *(const ushort4*)(q + 4);
    s[0] += b2f(a.x); s[1] += b2f(a.y); s[2] += b2f(a.z); s[3] += b2f(a.w);
    s[4] += b2f(b.x); s[5] += b2f(b.y); s[6] += b2f(b.z); s[7] += b2f(b.w);
  }
  long n = i >> 7;
  int f = (int)(i & 127);
  ushort4 o0, o1;
  o0.x = f2b(s[0]); o0.y = f2b(s[1]); o0.z = f2b(s[2]); o0.w = f2b(s[3]);
  o1.x = f2b(s[4]); o1.y = f2b(s[5]); o1.z = f2b(s[6]); o1.w = f2b(s[7]);
  unsigned short* d = out + n * (RR * FF) + r * FF + f;
  *(ushort4*)d = o0;
  *(ushort4*)(d + 4) = o1;
}

// ---- reduce Z bf16 partials of [NN][HDD] -> convout f32 + fused BN column stats ----
__global__ void k_redstats(const unsigned short* __restrict__ P, float* __restrict__ out,
                           float* __restrict__ cs, float* __restrict__ cs2, int Z) {
  __shared__ float sm[2][8][256];
  int cg = (threadIdx.x & 31) << 3;
  int rowt = threadIdx.x >> 5;
  int r0 = blockIdx.x * 32;
  float s[8] = {0, 0, 0, 0, 0, 0, 0, 0}, s2[8] = {0, 0, 0, 0, 0, 0, 0, 0};
  for (int j = 0; j < 4; j++) {
    long idx = (long)(r0 + rowt * 4 + j) * HDD + cg;
    float acc[8] = {0, 0, 0, 0, 0, 0, 0, 0};
    for (int z = 0; z < Z; z++) {
      const unsigned short* p = P + (size_t)z * ((long)NN * HDD) + idx;
      ushort4 a = *(const ushort4*)p;
      ushort4 b = *(const ushort4*)(p + 4);
      acc[0] += b2f(a.x); acc[1] += b2f(a.y); acc[2] += b2f(a.z); acc[3] += b2f(a.w);
      acc[4] += b2f(b.x); acc[5] += b2f(b.y); acc[6] += b2f(b.z); acc[7] += b2f(b.w);
    }
    float4 o0 = {acc[0], acc[1], acc[2], acc[3]};
    float4 o1 = {acc[4], acc[5], acc[6], acc[7]};
    *(float4*)(out + idx) = o0;
    *(float4*)(out + idx + 4) = o1;
#pragma unroll
    for (int i = 0; i < 8; i++) { s[i] += acc[i]; s2[i] += acc[i] * acc[i]; }
  }
#pragma unroll
  for (int i = 0; i < 8; i++) { sm[0][rowt][cg + i] = s[i]; sm[1][rowt][cg + i] = s2[i]; }
  __syncthreads();
  int c = threadIdx.x;
  float a0 = 0, a1 = 0;
#pragma unroll
  for (int t = 0; t < 8; t++) { a0 += sm[0][t][c]; a1 += sm[1][t][c]; }
  atomicAdd(&cs[c], a0);
  atomicAdd(&cs2[c], a1);
}

// ---- final: d_out = X + b3 + sum_Z bf16 partials [Z][NN][FF] ----
__global__ void k_red_out(const unsigned short* __restrict__ P, const float* __restrict__ X,
                          const float* __restrict__ b3, float* __restrict__ out, int Z) {
  long i = ((long)blockIdx.x * 256 + threadIdx.x) * 4;
  int f = (int)(i & 127);
  float4 s = *(const float4*)(X + i);
  s.x += b3[f]; s.y += b3[f + 1]; s.z += b3[f + 2]; s.w += b3[f + 3];
  for (int z = 0; z < Z; z++) {
    ushort4 v = *(const ushort4*)(P + (size_t)z * (NN * FF) + i);
    s.x += b2f(v.x); s.y += b2f(v.y); s.z += b2f(v.z); s.w += b2f(v.w);
  }
  *(float4*)(out + i) = s;
}

// ---- BN (batch stats) -> LN -> ELU -> bf16 [NN][HDD] ----
__global__ void k_bnlnelu(const float* __restrict__ x, const float* __restrict__ cs, const float* __restrict__ cs2,
                          const float* __restrict__ bg, const float* __restrict__ bb,
                          const float* __restrict__ lg, const float* __restrict__ lb,
                          unsigned short* __restrict__ out) {
  int wid = threadIdx.x >> 6, lane = threadIdx.x & 63;
  int n = blockIdx.x * 4 + wid;
  float y[4];
  float m = 0.f;
#pragma unroll
  for (int j = 0; j < 4; j++) {
    int c = lane + 64 * j;
    float mu = cs[c] * (1.0f / NN);
    float var = cs2[c] * (1.0f / NN) - mu * mu;
    float xv = x[(size_t)n * HDD + c];
    y[j] = (xv - mu) * rsqrtf(var + 1e-5f) * bg[c] + bb[c];
    m += y[j];
  }
  for (int off = 32; off; off >>= 1) m += __shfl_down(m, off);
  m = __shfl(m, 0) * (1.0f / HDD);
  float var = 0.f;
#pragma unroll
  for (int j = 0; j < 4; j++) { float d = y[j] - m; var += d * d; }
  for (int off = 32; off; off >>= 1) var += __shfl_down(var, off);
  var = __shfl(var, 0) * (1.0f / HDD);
  float inv = rsqrtf(var + 1e-5f);
#pragma unroll
  for (int j = 0; j < 4; j++) {
    int c = lane + 64 * j;
    float z = (y[j] - m) * inv * lg[c] + lb[c];
    z = z > 0.f ? z : expm1f(z);
    out[(size_t)n * HDD + c] = f2b(z);
  }
}

extern "C" void kernel_launch(void* const* d_in, const int* in_sizes, int n_in,
                              void* d_out, int out_size, void* d_ws, size_t ws_size,
                              hipStream_t stream) {
  const float* X   = (const float*)d_in[0];
  const float* H   = (const float*)d_in[1];
  const float* W1  = (const float*)d_in[2];
  const float* W2  = (const float*)d_in[3];
  const float* W3  = (const float*)d_in[4];
  const float* imp = (const float*)d_in[5];
  const float* b3  = (const float*)d_in[8];
  const float* bng = (const float*)d_in[9];
  const float* bnb = (const float*)d_in[10];
  const float* lng = (const float*)d_in[11];
  const float* lnb = (const float*)d_in[12];
  const float* rel = (const float*)d_in[13];
  (void)in_sizes; (void)n_in; (void)out_size; (void)ws_size;

  char* w = (char*)d_ws;
  size_t off = 0;
  auto alloc = [&](size_t bytes) -> void* {
    void* p = w + off;
    off += (bytes + 255) & ~(size_t)255;
    return p;
  };
  float* dvs  = (float*)alloc((size_t)RR * NN * 4);
  float* de   = (float*)alloc((size_t)RR * EE * 4);       // raw column counts
  float* cs   = (float*)alloc(2 * HDD * 4);               // [cs | cs2]
  unsigned long long* mask = (unsigned long long*)alloc((size_t)RR * NN * (EE / 64) * 8);
  unsigned short* theta  = (unsigned short*)alloc((size_t)RR * NN * EE * 2);   // 64MB
  unsigned short* thetaT = (unsigned short*)alloc((size_t)RR * NN * EE * 2);   // 64MB
  unsigned short* bufP = (unsigned short*)alloc((size_t)16 * NN * HDD * 2);    // 32MB bf16 partials
  unsigned short* bufC = (unsigned short*)alloc((size_t)RR * EE * HDD * 2);    // 4MB
  unsigned short* bufD = (unsigned short*)alloc((size_t)RR * EE * HDD * 2);    // 4MB
  unsigned short* bufE = (unsigned short*)alloc((size_t)RR * EE * HDD * 2);    // 4MB
  float* convout = (float*)alloc((size_t)NN * HDD * 4);                        // 4MB
  unsigned short* Xb  = (unsigned short*)alloc((size_t)NN * HDD * 2);
  unsigned short* XbT = (unsigned short*)alloc((size_t)NN * HDD * 2);
  unsigned short* W1catT = (unsigned short*)alloc((size_t)RR * FF * HDD * 2);
  unsigned short* W2T    = (unsigned short*)alloc((size_t)RR * HDD * HDD * 2);
  unsigned short* W3T    = (unsigned short*)alloc((size_t)RR * HDD * FF * 2);

  // ---- prep ----
  k_dvmask<<<(RR * NN) / 4, 256, 0, stream>>>(H, rel, dvs, mask);
  hipMemsetAsync(de, 0, (size_t)RR * EE * 4, stream);
  k_de_pop<<<dim3(EE / 64, NN / 256, RR), 256, 0, stream>>>(mask, de);
  k_build_theta_bits<<<dim3(EE / 64, NN / 64, RR), 256, 0, stream>>>(mask, dvs, de, rel, theta, thetaT);
  k_cvtT<<<dim3(FF / 64, NN / 64), 256, 0, stream>>>(X, XbT, NN, FF);  // XbT [128][4096]
  k_wprep<<<(RR * FF * HDD + RR * HDD * HDD + RR * HDD * FF) / 256, 256, 0, stream>>>(
      W1, W2, W3, imp, W1catT, W2T, W3T);

  // ---- layer 1 (128 -> 256) ----
  // tT[r][f][e] = sum_n XbT[f][n] thetaT[r][e][n]   M=128,N=2048,K=4096, z=(r,SK8) -> 512 blocks
  k_gemm3<<<dim3(1, EE / 128, RR * 8), 256, 0, stream>>>(
      XbT, thetaT, NN, 8, NN, NN, 0, (long)EE * NN, bufP, (long)FF * EE, EE);
  k_red_b<<<dim3((FF * EE) / 2048, RR), 256, 0, stream>>>(bufP, bufC, 8, (long)FF * EE);  // tTb
  // Hcat[n][r*128+f] = sum_e theta[r][n][e] tTb[r][f][e]   M=4096,N=128,K=2048, z=(r,SK2) -> 256 blocks
  k_gemm3<<<dim3(NN / 128, 1, RR * 2), 256, 0, stream>>>(
      theta, bufC, EE, 2, EE, EE, (long)NN * EE, (long)FF * EE, bufP, (long)NN * FF, FF);
  k_red_hcatb<<<dim3((NN * FF) / 2048, RR), 256, 0, stream>>>(bufP, bufD, 2);  // Hcatb [4096][512]
  // convout = Hcatb @ W1cat   M=4096,N=256,K=512, SK=4 -> 256 blocks (b1 dropped: BN-invariant)
  k_gemm3<<<dim3(NN / 128, HDD / 128, 4), 256, 0, stream>>>(
      bufD, W1catT, RR * FF, 4, RR * FF, RR * FF, 0, 0, bufP, (long)NN * HDD, HDD);
  hipMemsetAsync(cs, 0, 2 * HDD * 4, stream);
  k_redstats<<<NN / 32, 256, 0, stream>>>(bufP, convout, cs, cs + HDD, 4);
  k_bnlnelu<<<NN / 4, 256, 0, stream>>>(convout, cs, cs + HDD, bng, bnb, lng, lnb, Xb);
  k_trz<<<dim3(HDD / 64, NN / 64), 256, 0, stream>>>(Xb, XbT, NN, HDD);  // h^T

  // ---- layer 2 (256 -> 256) ----
  // t2[re][c] = sum_n thetaT-flat[re][n] h^T[c][n]   M=8192,N=256,K=4096, SK=4 -> 512 blocks
  k_gemm3<<<dim3(64, HDD / 128, 4), 256, 0, stream>>>(
      thetaT, XbT, NN, 4, NN, NN, 0, 0, bufP, (long)RR * EE * HDD, HDD);
  k_red_b<<<dim3((RR * EE * HDD) / 2048, 1), 256, 0, stream>>>(bufP, bufD, 4, (long)RR * EE * HDD);  // t2b
  // u[r][e][o] = sum_c t2b[r][e][c] W2T[r][o][c]   M=2048,N=256,K=256, z=(r,SK2) -> 256 blocks
  k_gemm3<<<dim3(EE / 128, HDD / 128, RR * 2), 256, 0, stream>>>(
      bufD, W2T, HDD, 2, HDD, HDD, (long)EE * HDD, (long)HDD * HDD, bufP, (long)EE * HDD, HDD);
  k_redT_b<<<dim3(HDD / 64, EE / 64, RR), 256, 0, stream>>>(bufP, bufE, 2, EE, HDD);  // uTb [r][o][e]
  // convout[n][o] = sum_r sum_e theta[r][n][e] uTb[r][o][e]   M=4096,N=256,K=2048, z=(r,SK2) -> 512 blocks
  k_gemm3<<<dim3(NN / 128, HDD / 128, RR * 2), 256, 0, stream>>>(
      theta, bufE, EE, 2, EE, EE, (long)NN * EE, (long)HDD * EE, bufP, (long)NN * HDD, HDD);
  hipMemsetAsync(cs, 0, 2 * HDD * 4, stream);
  k_redstats<<<NN / 32, 256, 0, stream>>>(bufP, convout, cs, cs + HDD, 8);
  k_bnlnelu<<<NN / 4, 256, 0, stream>>>(convout, cs, cs + HDD, bng + HDD, bnb + HDD, lng + HDD, lnb + HDD, Xb);

  // ---- layer 3 (256 -> 128), W3 applied first ----
  // y[r][n][o] = sum_c Xb[n][c] W3T[r][o][c]   M=4096,N=128,K=256, z=(r,SK2) -> 256 blocks
  k_gemm3<<<dim3(NN / 128, 1, RR * 2), 256, 0, stream>>>(
      Xb, W3T, HDD, 2, HDD, HDD, 0, (long)FF * HDD, bufP, (long)NN * FF, FF);
  k_redT_b<<<dim3(FF / 64, NN / 64, RR), 256, 0, stream>>>(bufP, bufD, 2, NN, FF);  // yTb [r][f][n]
  // s[r][e][f] = sum_n thetaT[r][e][n] yTb[r][f][n]   M=2048,N=128,K=4096, z=(r,SK4) -> 256 blocks
  k_gemm3<<<dim3(EE / 128, 1, RR * 4), 256, 0, stream>>>(
      thetaT, bufD, NN, 4, NN, NN, (long)EE * NN, (long)FF * NN, bufP, (long)EE * FF, FF);
  k_redT_b<<<dim3(FF / 64, EE / 64, RR), 256, 0, stream>>>(bufP, bufE, 4, EE, FF);  // sTb [r][f][e]
  // P[z] = theta[r] @ sTb[r] chunks   M=4096,N=128,K=2048, z=(r,SK2) -> 256 blocks
  k_gemm3<<<dim3(NN / 128, 1, RR * 2), 256, 0, stream>>>(
      theta, bufE, EE, 2, EE, EE, (long)NN * EE, (long)FF * EE, bufP, (long)NN * FF, FF);
  // d_out = X + b3 + sum_z P[z]
  k_red_out<<<(NN * FF) / 1024, 256, 0, stream>>>(bufP, X, b3, (float*)d_out, 8);
}

// Round 10
// 487.037 us; speedup vs baseline: 1.7315x; 1.0391x over previous
//
#include <hip/hip_runtime.h>
#include <hip/hip_bf16.h>

#define NN 4096
#define EE 2048
#define RR 4
#define FF 128
#define HDD 256

typedef __attribute__((ext_vector_type(4))) float floatx4;
typedef __attribute__((ext_vector_type(8))) __bf16 bf16x8;

#define AS1 __attribute__((address_space(1)))
#define AS3 __attribute__((address_space(3)))

__device__ __forceinline__ void async16(const void* g, void* l) {
  // global -> LDS direct copy, 16B per lane; LDS dest = wave-uniform base + lane*16
  __builtin_amdgcn_global_load_lds((const AS1 void*)(unsigned long long)(g),
                                   (AS3 void*)(unsigned int)(unsigned long long)(l),
                                   16, 0, 0);
}

__device__ inline unsigned short f2b(float x) {
  unsigned int u = __float_as_uint(x);
  unsigned int r = u + 0x7fffu + ((u >> 16) & 1u);
  return (unsigned short)(r >> 16);
}
__device__ inline float b2f(unsigned short u) { return __uint_as_float((unsigned int)u << 16); }

__device__ inline float rel_w(const float* rel, int r) {
  float m = fmaxf(fmaxf(rel[0], rel[1]), fmaxf(rel[2], rel[3]));
  float s = 0.f;
#pragma unroll
  for (int i = 0; i < RR; i++) s += expf(rel[i] - m);
  return expf(rel[r] - m) / s;
}

// ---- single pass over H: row sums -> dvs[r][n] = rw*rsqrt(rw*sum+eps), plus 0/1 bitmask ----
__global__ void k_dvmask(const float* __restrict__ H, const float* __restrict__ rel,
                         float* __restrict__ dvs, unsigned long long* __restrict__ mask) {
  int wave = (blockIdx.x << 2) | (threadIdx.x >> 6);  // = r*NN + n
  int lane = threadIdx.x & 63;
  int r = wave >> 12;
  const float* row = H + (size_t)wave * EE;
  unsigned long long* mrow = mask + (size_t)wave * (EE / 64);
  float s = 0.f;
  for (int j = 0; j < EE / 64; j++) {
    float h = row[j * 64 + lane];
    s += h;
    unsigned long long m = __ballot(h != 0.0f);
    if (lane == 0) mrow[j] = m;
  }
  for (int off = 32; off; off >>= 1) s += __shfl_down(s, off);
  if (lane == 0) {
    float rwr = rel_w(rel, r);
    dvs[wave] = rwr * rsqrtf(rwr * s + 1e-8f);
  }
}

// ---- column counts via ballot bit-transpose ----
__global__ void k_de_pop(const unsigned long long* __restrict__ mask, float* __restrict__ de_acc) {
  int wid = threadIdx.x >> 6, lane = threadIdx.x & 63;
  int wcol = blockIdx.x, r = blockIdx.z;
  int n0 = (blockIdx.y << 8) + (wid << 6);
  unsigned long long w = mask[(size_t)(r * NN + n0 + lane) * (EE / 64) + wcol];
  float cnt = 0.f;
#pragma unroll
  for (int b = 0; b < 64; b++) {
    unsigned long long m = __ballot(((w >> b) & 1ULL) != 0);
    if (lane == b) cnt = (float)__popcll(m);
  }
  atomicAdd(&de_acc[r * EE + (wcol << 6) + lane], cnt);
}

// ---- build theta[r][n][e] bf16 and thetaT[r][e][n]; de rsqrt fused ----
__global__ void k_build_theta_bits(const unsigned long long* __restrict__ mask,
                                   const float* __restrict__ dvs, const float* __restrict__ decnt,
                                   const float* __restrict__ rel,
                                   unsigned short* __restrict__ theta, unsigned short* __restrict__ thetaT) {
  __shared__ unsigned short tile[64][65];
  int r = blockIdx.z;
  int e0 = blockIdx.x * 64, n0 = blockIdx.y * 64;
  int tr = threadIdx.x >> 4, tc = threadIdx.x & 15;
  float rwr = rel_w(rel, r);
  float de0 = rsqrtf(rwr * decnt[r * EE + e0 + tc * 4 + 0] + 1e-8f);
  float de1 = rsqrtf(rwr * decnt[r * EE + e0 + tc * 4 + 1] + 1e-8f);
  float de2 = rsqrtf(rwr * decnt[r * EE + e0 + tc * 4 + 2] + 1e-8f);
  float de3 = rsqrtf(rwr * decnt[r * EE + e0 + tc * 4 + 3] + 1e-8f);
  int wcol = e0 >> 6;
#pragma unroll
  for (int i = 0; i < 4; i++) {
    int n = n0 + tr + 16 * i;
    unsigned long long w = mask[((size_t)r * NN + n) * (EE / 64) + wcol];
    float d = dvs[r * NN + n];
    unsigned short b0 = ((w >> (tc * 4 + 0)) & 1) ? f2b(d * de0) : 0;
    unsigned short b1 = ((w >> (tc * 4 + 1)) & 1) ? f2b(d * de1) : 0;
    unsigned short b2 = ((w >> (tc * 4 + 2)) & 1) ? f2b(d * de2) : 0;
    unsigned short b3 = ((w >> (tc * 4 + 3)) & 1) ? f2b(d * de3) : 0;
    ushort4 o; o.x = b0; o.y = b1; o.z = b2; o.w = b3;
    *(ushort4*)(theta + ((size_t)r * NN + n) * EE + e0 + tc * 4) = o;
    tile[tr + 16 * i][tc * 4 + 0] = b0;
    tile[tr + 16 * i][tc * 4 + 1] = b1;
    tile[tr + 16 * i][tc * 4 + 2] = b2;
    tile[tr + 16 * i][tc * 4 + 3] = b3;
  }
  __syncthreads();
#pragma unroll
  for (int i = 0; i < 4; i++) {
    int e = e0 + tr + 16 * i;
    ushort4 o;
    o.x = tile[tc * 4 + 0][tr + 16 * i];
    o.y = tile[tc * 4 + 1][tr + 16 * i];
    o.z = tile[tc * 4 + 2][tr + 16 * i];
    o.w = tile[tc * 4 + 3][tr + 16 * i];
    *(ushort4*)(thetaT + ((size_t)r * EE + e) * NN + n0 + tc * 4) = o;
  }
}

// ---- f32 [M][C] -> bf16 [C][M] (transpose+convert) ----
__global__ void k_cvtT(const float* __restrict__ src, unsigned short* __restrict__ dst, int M, int C) {
  __shared__ unsigned short tile[64][65];
  int c0 = blockIdx.x * 64, m0 = blockIdx.y * 64;
  int tr = threadIdx.x >> 4, tc = threadIdx.x & 15;
#pragma unroll
  for (int i = 0; i < 4; i++) {
    int m = m0 + tr + 16 * i;
    float4 v = *(const float4*)(src + (size_t)m * C + c0 + tc * 4);
    tile[tr + 16 * i][tc * 4 + 0] = f2b(v.x);
    tile[tr + 16 * i][tc * 4 + 1] = f2b(v.y);
    tile[tr + 16 * i][tc * 4 + 2] = f2b(v.z);
    tile[tr + 16 * i][tc * 4 + 3] = f2b(v.w);
  }
  __syncthreads();
#pragma unroll
  for (int i = 0; i < 4; i++) {
    int c = c0 + tr + 16 * i;
    ushort4 v;
    v.x = tile[tc * 4 + 0][tr + 16 * i];
    v.y = tile[tc * 4 + 1][tr + 16 * i];
    v.z = tile[tc * 4 + 2][tr + 16 * i];
    v.w = tile[tc * 4 + 3][tr + 16 * i];
    *(ushort4*)(dst + (size_t)c * M + m0 + tc * 4) = v;
  }
}

// ---- bf16 [M][C] -> bf16 [C][M] ----
__global__ void k_trz(const unsigned short* __restrict__ src, unsigned short* __restrict__ dst, int M, int C) {
  __shared__ unsigned short tile[64][65];
  int c0 = blockIdx.x * 64, m0 = blockIdx.y * 64;
  int tr = threadIdx.x >> 4, tc = threadIdx.x & 15;
#pragma unroll
  for (int i = 0; i < 4; i++) {
    int m = m0 + tr + 16 * i;
    ushort4 v = *(const ushort4*)(src + (size_t)m * C + c0 + tc * 4);
    tile[tr + 16 * i][tc * 4 + 0] = v.x;
    tile[tr + 16 * i][tc * 4 + 1] = v.y;
    tile[tr + 16 * i][tc * 4 + 2] = v.z;
    tile[tr + 16 * i][tc * 4 + 3] = v.w;
  }
  __syncthreads();
#pragma unroll
  for (int i = 0; i < 4; i++) {
    int c = c0 + tr + 16 * i;
    ushort4 v;
    v.x = tile[tc * 4 + 0][tr + 16 * i];
    v.y = tile[tc * 4 + 1][tr + 16 * i];
    v.z = tile[tc * 4 + 2][tr + 16 * i];
    v.w = tile[tc * 4 + 3][tr + 16 * i];
    *(ushort4*)(dst + (size_t)c * M + m0 + tc * 4) = v;
  }
}

// ---- all three weight transforms in ONE launch ----
__global__ void k_wprep(const float* __restrict__ W1, const float* __restrict__ W2,
                        const float* __restrict__ W3, const float* __restrict__ imp,
                        unsigned short* __restrict__ W1catT, unsigned short* __restrict__ W2T,
                        unsigned short* __restrict__ W3T) {
  int idx = blockIdx.x * 256 + threadIdx.x;
  if (idx < RR * FF * HDD) {
    int o = idx % HDD, f = (idx / HDD) % FF, r = idx / (HDD * FF);
    float sg = 1.0f / (1.0f + expf(-imp[r]));
    W1catT[(size_t)o * (RR * FF) + r * FF + f] = f2b(sg * W1[((size_t)r * FF + f) * HDD + o]);
  } else if (idx < RR * FF * HDD + RR * HDD * HDD) {
    int j = idx - RR * FF * HDD;
    int c = j % HDD, o = (j / HDD) % HDD, r = j / (HDD * HDD);
    float sg = 1.0f / (1.0f + expf(-imp[RR + r]));
    W2T[j] = f2b(sg * W2[((size_t)r * HDD + c) * HDD + o]);
  } else {
    int j = idx - RR * FF * HDD - RR * HDD * HDD;
    int c = j % HDD, o = (j / HDD) % FF, r = j / (HDD * FF);
    float sg = 1.0f / (1.0f + expf(-imp[2 * RR + r]));
    W3T[j] = f2b(sg * W3[((size_t)r * HDD + c) * FF + o]);
  }
}

// ---------------- MFMA GEMM, 128x128 tile, BK=64, COALESCED async staging (XOR swizzle) ----------------
// Staging: 8 lanes cover one row's 64 k-elems (contiguous 128B), 8 rows/instr, chunk c^r8 swizzle.
// z = zr*SK + kz. P[z][c_ps] bf16, plain stores.
__global__ __launch_bounds__(256) void k_gemm3(
    const unsigned short* __restrict__ A, const unsigned short* __restrict__ BT,
    int K, int SK, int lda, int ldb, long a_rs, long b_rs,
    unsigned short* __restrict__ P, long c_ps, int ldc) {
  __shared__ unsigned short Al[128 * 64];
  __shared__ unsigned short Bl[128 * 64];
  int tid = threadIdx.x, wid = tid >> 6, lane = tid & 63;
  int m0 = blockIdx.x << 7, n0 = blockIdx.y << 7;
  int z = blockIdx.z, zr = z / SK, kz = z - zr * SK;
  int Kc = K / SK;
  int r8 = lane >> 3, c8 = lane & 7;
  int swz = ((c8 ^ r8) << 3);               // element offset of this lane's 16B chunk within the row
  const unsigned short* Ab = A + (size_t)zr * a_rs + (size_t)m0 * lda + (size_t)kz * Kc;
  const unsigned short* Bb = BT + (size_t)zr * b_rs + (size_t)n0 * ldb + (size_t)kz * Kc;
  int wm = (wid >> 1) << 6, wn = (wid & 1) << 6;
  int fm = lane & 15, quad = lane >> 4;
  int f7 = fm & 7;
  floatx4 acc[4][4];
#pragma unroll
  for (int i = 0; i < 4; i++)
#pragma unroll
    for (int j = 0; j < 4; j++) acc[i][j] = (floatx4){0.f, 0.f, 0.f, 0.f};
  for (int k0 = 0; k0 < Kc; k0 += 64) {
#pragma unroll
    for (int t = 0; t < 4; t++) {
      int rbase = (wid << 5) + (t << 3);    // 0..120, wave covers 32 rows in 4 instrs
      int row = rbase + r8;
      async16(Ab + (size_t)row * lda + k0 + swz, &Al[rbase * 64 + lane * 8]);
      async16(Bb + (size_t)row * ldb + k0 + swz, &Bl[rbase * 64 + lane * 8]);
    }
    __syncthreads();  // vmcnt(0) drain before s_barrier -> LDS writes visible
#pragma unroll
    for (int ks = 0; ks < 2; ks++) {
      int kg = (ks << 2) | quad;
      int ko = ((kg ^ f7) << 3);
      bf16x8 a[4], b[4];
#pragma unroll
      for (int i = 0; i < 4; i++) {
        a[i] = *(const bf16x8*)&Al[(wm + i * 16 + fm) * 64 + ko];
        b[i] = *(const bf16x8*)&Bl[(wn + i * 16 + fm) * 64 + ko];
      }
#pragma unroll
      for (int i = 0; i < 4; i++)
#pragma unroll
        for (int j = 0; j < 4; j++)
          acc[i][j] = __builtin_amdgcn_mfma_f32_16x16x32_bf16(a[i], b[j], acc[i][j], 0, 0, 0);
    }
    __syncthreads();
  }
  unsigned short* Cb = P + (size_t)z * c_ps;
#pragma unroll
  for (int mi = 0; mi < 4; mi++)
#pragma unroll
    for (int ni = 0; ni < 4; ni++)
#pragma unroll
      for (int v = 0; v < 4; v++) {
        int row = m0 + wm + mi * 16 + quad * 4 + v;
        int col = n0 + wn + ni * 16 + fm;
        Cb[(size_t)row * ldc + col] = f2b(acc[mi][ni][v]);
      }
}

// ---- reduce SK bf16 partials per zr -> bf16 out[zr][region] ----
__global__ void k_red_b(const unsigned short* __restrict__ P, unsigned short* __restrict__ out,
                        int SK, long region) {
  long i = ((long)blockIdx.x * 256 + threadIdx.x) * 8;
  int zr = blockIdx.y;
  const unsigned short* p = P + (size_t)zr * SK * region + i;
  float s[8] = {0, 0, 0, 0, 0, 0, 0, 0};
  for (int k = 0; k < SK; k++) {
    const unsigned short* q = p + (size_t)k * region;
    ushort4 a = *(const ushort4*)q;
    ushort4 b = *(const ushort4*)(q + 4);
    s[0] += b2f(a.x); s[1] += b2f(a.y); s[2] += b2f(a.z); s[3] += b2f(a.w);
    s[4] += b2f(b.x); s[5] += b2f(b.y); s[6] += b2f(b.z); s[7] += b2f(b.w);
  }
  ushort4 o0, o1;
  o0.x = f2b(s[0]); o0.y = f2b(s[1]); o0.z = f2b(s[2]); o0.w = f2b(s[3]);
  o1.x = f2b(s[4]); o1.y = f2b(s[5]); o1.z = f2b(s[6]); o1.w = f2b(s[7]);
  unsigned short* d = out + (size_t)zr * region + i;
  *(ushort4*)d = o0;
  *(ushort4*)(d + 4) = o1;
}

// ---- reduce SK bf16 partials per r of [NN][FF] -> Hcat[n][r*FF+f] bf16 ----
__global__ void k_red_hcatb(const unsigned short* __restrict__ P, unsigned short* __restrict__ out, int SK) {
  long i = ((long)blockIdx.x * 256 + threadIdx.x) * 8;
  int r = blockIdx.y;
  const unsigned short* p = P + (size_t)r * SK * (NN * FF) + i;
  float s[8] = {0, 0, 0, 0, 0, 0, 0, 0};
  for (int k = 0; k < SK; k++) {
    const unsigned short* q = p + (size_t)k * (NN * FF);
    ushort4 a = *(const ushort4*)q;
    ushort4 b = *(const ushort4*)(q + 4);
    s[0] += b2f(a.x); s[1] += b2f(a.y); s[2] += b2f(a.z); s[3] += b2f(a.w);
    s[4] += b2f(b.x); s[5] += b2f(b.y); s[6] += b2f(b.z); s[7] += b2f(b.w);
  }
  long n = i >> 7;
  int f = (int)(i & 127);
  ushort4 o0, o1;
  o0.x = f2b(s[0]); o0.y = f2b(s[1]); o0.z = f2b(s[2]); o0.w = f2b(s[3]);
  o1.x = f2b(s[4]); o1.y = f2b(s[5]); o1.z = f2b(s[6]); o1.w = f2b(s[7]);
  unsigned short* d = out + n * (RR * FF) + r * FF + f;
  *(ushort4*)d = o0;
  *(ushort4*)(d + 4) = o1;
}

// ---- reduce Z bf16 partials of [NN][HDD] -> convout f32 + fused BN column stats ----
__global__ void k_redstats(const unsigned short* __restrict__ P, float* __restrict__ out,
                           float* __restrict__ cs, float* __restrict__ cs2, int Z) {
  __shared__ float sm[2][8][256];
  int cg = (threadIdx.x & 31) << 3;
  int rowt = threadIdx.x >> 5;
  int r0 = blockIdx.x * 32;
  float s[8] = {0, 0, 0, 0, 0, 0, 0, 0}, s2[8] = {0, 0, 0, 0, 0, 0, 0, 0};
  for (int j = 0; j < 4; j++) {
    long idx = (long)(r0 + rowt * 4 + j) * HDD + cg;
    float acc[8] = {0, 0, 0, 0, 0, 0, 0, 0};
    for (int z = 0; z < Z; z++) {
      const unsigned short* p = P + (size_t)z * ((long)NN * HDD) + idx;
      ushort4 a = *(const ushort4*)p;
      ushort4 b = *(const ushort4*)(p + 4);
      acc[0] += b2f(a.x); acc[1] += b2f(a.y); acc[2] += b2f(a.z); acc[3] += b2f(a.w);
      acc[4] += b2f(b.x); acc[5] += b2f(b.y); acc[6] += b2f(b.z); acc[7] += b2f(b.w);
    }
    float4 o0 = {acc[0], acc[1], acc[2], acc[3]};
    float4 o1 = {acc[4], acc[5], acc[6], acc[7]};
    *(float4*)(out + idx) = o0;
    *(float4*)(out + idx + 4) = o1;
#pragma unroll
    for (int i = 0; i < 8; i++) { s[i] += acc[i]; s2[i] += acc[i] * acc[i]; }
  }
#pragma unroll
  for (int i = 0; i < 8; i++) { sm[0][rowt][cg + i] = s[i]; sm[1][rowt][cg + i] = s2[i]; }
  __syncthreads();
  int c = threadIdx.x;
  float a0 = 0, a1 = 0;
#pragma unroll
  for (int t = 0; t < 8; t++) { a0 += sm[0][t][c]; a1 += sm[1][t][c]; }
  atomicAdd(&cs[c], a0);
  atomicAdd(&cs2[c], a1);
}

// ---- final: d_out = X + b3 + sum_Z bf16 partials [Z][NN][FF] ----
__global__ void k_red_out(const unsigned short* __restrict__ P, const float* __restrict__ X,
                          const float* __restrict__ b3, float* __restrict__ out, int Z) {
  long i = ((long)blockIdx.x * 256 + threadIdx.x) * 4;
  int f = (int)(i & 127);
  float4 s = *(const float4*)(X + i);
  s.x += b3[f]; s.y += b3[f + 1]; s.z += b3[f + 2]; s.w += b3[f + 3];
  for (int z = 0; z < Z; z++) {
    ushort4 v = *(const ushort4*)(P + (size_t)z * (NN * FF) + i);
    s.x += b2f(v.x); s.y += b2f(v.y); s.z += b2f(v.z); s.w += b2f(v.w);
  }
  *(float4*)(out + i) = s;
}

// ---- BN (batch stats) -> LN -> ELU -> bf16 [NN][HDD] ----
__global__ void k_bnlnelu(const float* __restrict__ x, const float* __restrict__ cs, const float* __restrict__ cs2,
                          const float* __restrict__ bg, const float* __restrict__ bb,
                          const float* __restrict__ lg, const float* __restrict__ lb,
                          unsigned short* __restrict__ out) {
  int wid = threadIdx.x >> 6, lane = threadIdx.x & 63;
  int n = blockIdx.x * 4 + wid;
  float y[4];
  float m = 0.f;
#pragma unroll
  for (int j = 0; j < 4; j++) {
    int c = lane + 64 * j;
    float mu = cs[c] * (1.0f / NN);
    float var = cs2[c] * (1.0f / NN) - mu * mu;
    float xv = x[(size_t)n * HDD + c];
    y[j] = (xv - mu) * rsqrtf(var + 1e-5f) * bg[c] + bb[c];
    m += y[j];
  }
  for (int off = 32; off; off >>= 1) m += __shfl_down(m, off);
  m = __shfl(m, 0) * (1.0f / HDD);
  float var = 0.f;
#pragma unroll
  for (int j = 0; j < 4; j++) { float d = y[j] - m; var += d * d; }
  for (int off = 32; off; off >>= 1) var += __shfl_down(var, off);
  var = __shfl(var, 0) * (1.0f / HDD);
  float inv = rsqrtf(var + 1e-5f);
#pragma unroll
  for (int j = 0; j < 4; j++) {
    int c = lane + 64 * j;
    float z = (y[j] - m) * inv * lg[c] + lb[c];
    z = z > 0.f ? z : expm1f(z);
    out[(size_t)n * HDD + c] = f2b(z);
  }
}

extern "C" void kernel_launch(void* const* d_in, const int* in_sizes, int n_in,
                              void* d_out, int out_size, void* d_ws, size_t ws_size,
                              hipStream_t stream) {
  const float* X   = (const float*)d_in[0];
  const float* H   = (const float*)d_in[1];
  const float* W1  = (const float*)d_in[2];
  const float* W2  = (const float*)d_in[3];
  const float* W3  = (const float*)d_in[4];
  const float* imp = (const float*)d_in[5];
  const float* b3  = (const float*)d_in[8];
  const float* bng = (const float*)d_in[9];
  const float* bnb = (const float*)d_in[10];
  const float* lng = (const float*)d_in[11];
  const float* lnb = (const float*)d_in[12];
  const float* rel = (const float*)d_in[13];
  (void)in_sizes; (void)n_in; (void)out_size; (void)ws_size;

  char* w = (char*)d_ws;
  size_t off = 0;
  auto alloc = [&](size_t bytes) -> void* {
    void* p = w + off;
    off += (bytes + 255) & ~(size_t)255;
    return p;
  };
  float* dvs  = (float*)alloc((size_t)RR * NN * 4);
  float* de   = (float*)alloc((size_t)RR * EE * 4);       // raw column counts
  float* cs   = (float*)alloc(2 * HDD * 4);               // [cs | cs2]
  unsigned long long* mask = (unsigned long long*)alloc((size_t)RR * NN * (EE / 64) * 8);
  unsigned short* theta  = (unsigned short*)alloc((size_t)RR * NN * EE * 2);   // 64MB
  unsigned short* thetaT = (unsigned short*)alloc((size_t)RR * NN * EE * 2);   // 64MB
  unsigned short* bufP = (unsigned short*)alloc((size_t)16 * NN * HDD * 2);    // 32MB bf16 partials
  unsigned short* bufC = (unsigned short*)alloc((size_t)RR * EE * HDD * 2);    // 4MB
  unsigned short* bufD = (unsigned short*)alloc((size_t)RR * EE * HDD * 2);    // 4MB
  unsigned short* bufE = (unsigned short*)alloc((size_t)RR * EE * HDD * 2);    // 4MB
  float* convout = (float*)alloc((size_t)NN * HDD * 4);                        // 4MB
  unsigned short* Xb  = (unsigned short*)alloc((size_t)NN * HDD * 2);
  unsigned short* XbT = (unsigned short*)alloc((size_t)NN * HDD * 2);
  unsigned short* W1catT = (unsigned short*)alloc((size_t)RR * FF * HDD * 2);
  unsigned short* W2T    = (unsigned short*)alloc((size_t)RR * HDD * HDD * 2);
  unsigned short* W3T    = (unsigned short*)alloc((size_t)RR * HDD * FF * 2);

  // ---- prep ----
  k_dvmask<<<(RR * NN) / 4, 256, 0, stream>>>(H, rel, dvs, mask);
  hipMemsetAsync(de, 0, (size_t)RR * EE * 4, stream);
  k_de_pop<<<dim3(EE / 64, NN / 256, RR), 256, 0, stream>>>(mask, de);
  k_build_theta_bits<<<dim3(EE / 64, NN / 64, RR), 256, 0, stream>>>(mask, dvs, de, rel, theta, thetaT);
  k_cvtT<<<dim3(FF / 64, NN / 64), 256, 0, stream>>>(X, XbT, NN, FF);  // XbT [128][4096]
  k_wprep<<<(RR * FF * HDD + RR * HDD * HDD + RR * HDD * FF) / 256, 256, 0, stream>>>(
      W1, W2, W3, imp, W1catT, W2T, W3T);

  // ---- layer 1 (128 -> 256) ----
  // tT[r][f][e] = sum_n XbT[f][n] thetaT[r][e][n]   M=128,N=2048,K=4096, z=(r,SK8) -> 512 blocks
  k_gemm3<<<dim3(1, EE / 128, RR * 8), 256, 0, stream>>>(
      XbT, thetaT, NN, 8, NN, NN, 0, (long)EE * NN, bufP, (long)FF * EE, EE);
  k_red_b<<<dim3((FF * EE) / 2048, RR), 256, 0, stream>>>(bufP, bufC, 8, (long)FF * EE);  // tTb [r][f][e]
  // Hcat[n][r*128+f] = sum_e theta[r][n][e] tTb[r][f][e]   M=4096,N=128,K=2048, z=(r,SK2) -> 256 blocks
  k_gemm3<<<dim3(NN / 128, 1, RR * 2), 256, 0, stream>>>(
      theta, bufC, EE, 2, EE, EE, (long)NN * EE, (long)FF * EE, bufP, (long)NN * FF, FF);
  k_red_hcatb<<<dim3((NN * FF) / 2048, RR), 256, 0, stream>>>(bufP, bufD, 2);  // Hcatb [4096][512]
  // convout = Hcatb @ W1cat   M=4096,N=256,K=512, SK=4 -> 256 blocks (b1 dropped: BN-invariant)
  k_gemm3<<<dim3(NN / 128, HDD / 128, 4), 256, 0, stream>>>(
      bufD, W1catT, RR * FF, 4, RR * FF, RR * FF, 0, 0, bufP, (long)NN * HDD, HDD);
  hipMemsetAsync(cs, 0, 2 * HDD * 4, stream);
  k_redstats<<<NN / 32, 256, 0, stream>>>(bufP, convout, cs, cs + HDD, 4);
  k_bnlnelu<<<NN / 4, 256, 0, stream>>>(convout, cs, cs + HDD, bng, bnb, lng, lnb, Xb);
  k_trz<<<dim3(HDD / 64, NN / 64), 256, 0, stream>>>(Xb, XbT, NN, HDD);  // h^T [256][4096]

  // ---- layer 2 (256 -> 256) ----
  // t2[re][c] = sum_n thetaT-flat[re][n] h^T[c][n]   M=8192,N=256,K=4096, SK=4 -> 512 blocks
  k_gemm3<<<dim3(64, HDD / 128, 4), 256, 0, stream>>>(
      thetaT, XbT, NN, 4, NN, NN, 0, 0, bufP, (long)RR * EE * HDD, HDD);
  k_red_b<<<dim3((RR * EE * HDD) / 2048, 1), 256, 0, stream>>>(bufP, bufD, 4, (long)RR * EE * HDD);  // t2b [r][e][c]
  // uT[r][o][e] = sum_c W2T[r][o][c] t2b[r][e][c]   TRANSPOSED OUTPUT: A=W2T, B=t2b
  //   M=256,N=2048,K=256, SK=1, z=r -> 128 blocks, direct bf16 write (no reduce)
  k_gemm3<<<dim3(HDD / 128, EE / 128, RR), 256, 0, stream>>>(
      W2T, bufD, HDD, 1, HDD, HDD, (long)HDD * HDD, (long)EE * HDD, bufE, (long)HDD * EE, EE);
  // convout[n][o] = sum_r sum_e theta[r][n][e] uT[r][o][e]   M=4096,N=256,K=2048, z=(r,SK2) -> 512 blocks
  k_gemm3<<<dim3(NN / 128, HDD / 128, RR * 2), 256, 0, stream>>>(
      theta, bufE, EE, 2, EE, EE, (long)NN * EE, (long)HDD * EE, bufP, (long)NN * HDD, HDD);
  hipMemsetAsync(cs, 0, 2 * HDD * 4, stream);
  k_redstats<<<NN / 32, 256, 0, stream>>>(bufP, convout, cs, cs + HDD, 8);
  k_bnlnelu<<<NN / 4, 256, 0, stream>>>(convout, cs, cs + HDD, bng + HDD, bnb + HDD, lng + HDD, lnb + HDD, Xb);

  // ---- layer 3 (256 -> 128), W3 applied first ----
  // yT[r][f][n] = sum_c W3T[r][f][c] Xb[n][c]   TRANSPOSED OUTPUT: A=W3T, B=Xb
  //   M=128,N=4096,K=256, SK=1, z=r -> 128 blocks, direct bf16 write (no reduce)
  k_gemm3<<<dim3(1, NN / 128, RR), 256, 0, stream>>>(
      W3T, Xb, HDD, 1, HDD, HDD, (long)FF * HDD, 0, bufD, (long)FF * NN, NN);
  // sT[r][f][e] = sum_n yT[r][f][n] thetaT[r][e][n]   A=yT, B=thetaT
  //   M=128,N=2048,K=4096, z=(r,SK4) -> 256 blocks
  k_gemm3<<<dim3(1, EE / 128, RR * 4), 256, 0, stream>>>(
      bufD, thetaT, NN, 4, NN, NN, (long)FF * NN, (long)EE * NN, bufP, (long)FF * EE, EE);
  k_red_b<<<dim3((FF * EE) / 2048, RR), 256, 0, stream>>>(bufP, bufC, 4, (long)FF * EE);  // sTb [r][f][e]
  // P[z] = theta[r] @ sTb[r] chunks   M=4096,N=128,K=2048, z=(r,SK2) -> 256 blocks
  k_gemm3<<<dim3(NN / 128, 1, RR * 2), 256, 0, stream>>>(
      theta, bufC, EE, 2, EE, EE, (long)NN * EE, (long)FF * EE, bufP, (long)NN * FF, FF);
  // d_out = X + b3 + sum_z P[z]
  k_red_out<<<(NN * FF) / 1024, 256, 0, stream>>>(bufP, X, b3, (float*)d_out, 8);
}